// Round 2
// baseline (766.282 us; speedup 1.0000x reference)
//
#include <hip/hip_runtime.h>
#include <math.h>

#define N_ROWS 131072
#define DIM 64
#define KM1 1023

// ---- ws layout (bytes) ----
#define DITH_OFF 0         // float[1023*64] = 261888
#define D2_OFF   262144    // float[1023]
#define CNT_OFF  266240    // u32[1024]
#define IDX_OFF  270336    // i32[131072]

// Opacity guard: prevents ffp-contract=fast from fusing a mul into a
// following add (which would change rounding vs numpy's separate ops).
#define OPQ(x) asm volatile("" : "+v"(x))

// numpy pairwise_sum for n=64 f32, bit-exact replica:
// 8 accumulators stride-8, then ((r0+r1)+(r2+r3))+((r4+r5)+(r6+r7)).
__device__ __forceinline__ float np_sum64(const float* b) {
    float r[8];
    #pragma unroll
    for (int j = 0; j < 8; ++j) r[j] = b[j];
    #pragma unroll
    for (int i = 8; i < 64; i += 8) {
        #pragma unroll
        for (int j = 0; j < 8; ++j) r[j] = __fadd_rn(r[j], b[i + j]);
    }
    return __fadd_rn(__fadd_rn(__fadd_rn(r[0], r[1]), __fadd_rn(r[2], r[3])),
                     __fadd_rn(__fadd_rn(r[4], r[5]), __fadd_rn(r[6], r[7])));
}

// Kernel A: dithered codebook (exact numpy op order), per-k dsum, zero counts.
__global__ void prep_kernel(const float* __restrict__ cb,
                            const float* __restrict__ dither,
                            float* __restrict__ dith,
                            float* __restrict__ d2,
                            unsigned* __restrict__ counts) {
    int t = blockIdx.x * 256 + threadIdx.x;   // grid 4*256 = 1024
    if (t < 1024) counts[t] = 0u;
    if (t >= KM1) return;
    float tt = dither[t];
    float b[64];
    #pragma unroll 8
    for (int i = 0; i < 64; ++i) {
        float lo = cb[t * 64 + i];
        float hi = cb[t * 64 + 64 + i];
        float hl = __fsub_rn(hi, lo);
        float p  = __fmul_rn(tt, hl);
        OPQ(p);
        float dv = __fadd_rn(lo, p);
        OPQ(dv);
        dith[t * 64 + i] = dv;
        float bb = __fmul_rn(dv, dv);
        OPQ(bb);
        b[i] = bb;
    }
    d2[t] = np_sum64(b);
}

// Kernel B: per-row argmin of fl(fl(zsum + dsum_k) - gemm_chain(2z, d_k)),
// bit-exact vs numpy f32 reference; first-index tie-break via strict <.
__global__ void __launch_bounds__(256)
argmin_kernel(const float* __restrict__ z_g,
              const float* __restrict__ dith,
              const float* __restrict__ d2,
              int* __restrict__ idx_out) {
    int row = blockIdx.x * 256 + threadIdx.x;
    float z[DIM];
    const float4* zr = (const float4*)(z_g + (size_t)row * DIM);
    #pragma unroll
    for (int j = 0; j < 16; ++j) {
        float4 v = zr[j];
        z[4 * j + 0] = v.x; z[4 * j + 1] = v.y;
        z[4 * j + 2] = v.z; z[4 * j + 3] = v.w;
    }
    // zsum: numpy 8-accumulator pairwise over fl(z_i^2), no temp array.
    float r[8];
    #pragma unroll
    for (int j = 0; j < 8; ++j) {
        float bb = __fmul_rn(z[j], z[j]); OPQ(bb); r[j] = bb;
    }
    #pragma unroll
    for (int i = 8; i < 64; i += 8) {
        #pragma unroll
        for (int j = 0; j < 8; ++j) {
            float bb = __fmul_rn(z[i + j], z[i + j]); OPQ(bb);
            r[j] = __fadd_rn(r[j], bb);
        }
    }
    float zsum = __fadd_rn(
        __fadd_rn(__fadd_rn(r[0], r[1]), __fadd_rn(r[2], r[3])),
        __fadd_rn(__fadd_rn(r[4], r[5]), __fadd_rn(r[6], r[7])));
    // tz = 2z (exact), in place.
    #pragma unroll
    for (int i = 0; i < 64; ++i) z[i] = __fadd_rn(z[i], z[i]);

    float best = INFINITY;
    int bidx = 0;
    int k = 0;
    for (; k + 4 <= KM1; k += 4) {
        const float* __restrict__ p0 = dith + (size_t)k * 64;
        float a0 = 0.f, a1 = 0.f, a2 = 0.f, a3 = 0.f;
        #pragma unroll
        for (int i = 0; i < 64; ++i) {
            float zi = z[i];
            a0 = fmaf(zi, p0[i],        a0);   // strict sequential FMA chain
            a1 = fmaf(zi, p0[64 + i],   a1);   // (replicates sgemm microkernel)
            a2 = fmaf(zi, p0[128 + i],  a2);
            a3 = fmaf(zi, p0[192 + i],  a3);
        }
        float D0 = __fsub_rn(__fadd_rn(zsum, d2[k]),     a0);
        float D1 = __fsub_rn(__fadd_rn(zsum, d2[k + 1]), a1);
        float D2 = __fsub_rn(__fadd_rn(zsum, d2[k + 2]), a2);
        float D3 = __fsub_rn(__fadd_rn(zsum, d2[k + 3]), a3);
        if (D0 < best) { best = D0; bidx = k; }
        if (D1 < best) { best = D1; bidx = k + 1; }
        if (D2 < best) { best = D2; bidx = k + 2; }
        if (D3 < best) { best = D3; bidx = k + 3; }
    }
    for (; k < KM1; ++k) {                    // tail: 1020..1022
        const float* __restrict__ p0 = dith + (size_t)k * 64;
        float a0 = 0.f;
        #pragma unroll
        for (int i = 0; i < 64; ++i) a0 = fmaf(z[i], p0[i], a0);
        float D0 = __fsub_rn(__fadd_rn(zsum, d2[k]), a0);
        if (D0 < best) { best = D0; bidx = k; }
    }
    idx_out[row] = bidx;
}

// Kernel C: per-row finalize. One wave per row (lane = dim).
__global__ void __launch_bounds__(256)
finalize_kernel(const float* __restrict__ z_g,
                const float* __restrict__ cb,
                const float* __restrict__ dither,
                const float* __restrict__ n1_g,
                const float* __restrict__ n2_g,
                const int* __restrict__ idx_arr,
                float* __restrict__ zq_out,
                float* __restrict__ idxf_out,
                unsigned* __restrict__ counts) {
    int wid = (blockIdx.x * 256 + threadIdx.x) >> 6;   // row
    int lane = threadIdx.x & 63;
    int idx = idx_arr[wid];
    size_t base = (size_t)wid * DIM + lane;
    float z  = z_g[base];
    float n1 = n1_g[base];
    float n2 = n2_g[base];
    float c1 = cb[idx * DIM + lane];
    float c2 = cb[(idx + 1) * DIM + lane];
    float lam = dither[idx];
    float d1 = c1 - z, d2v = c2 - z;
    float r1 = n1 + d1, r2 = n2 + d2v;
    float s_r1 = r1 * r1, s_r2 = r2 * r2, s_d1 = d1 * d1, s_d2 = d2v * d2v;
    #pragma unroll
    for (int m = 32; m; m >>= 1) {
        s_r1 += __shfl_xor(s_r1, m, 64);
        s_r2 += __shfl_xor(s_r2, m, 64);
        s_d1 += __shfl_xor(s_d1, m, 64);
        s_d2 += __shfl_xor(s_d2, m, 64);
    }
    float em1 = sqrtf(s_d1), em2 = sqrtf(s_d2);
    float nr1 = fmaxf(sqrtf(s_r1), 1e-12f);
    float nr2 = fmaxf(sqrtf(s_r2), 1e-12f);
    float zq = z + em1 * (1.f - lam) * (r1 / nr1) + em2 * lam * (r2 / nr2);
    zq_out[base] = zq;
    if (lane == 0) {
        idxf_out[wid] = (float)idx;
        atomicAdd(&counts[idx], 1u);
    }
}

// Kernel D: perplexity from counts.
__global__ void ppl_kernel(const unsigned* __restrict__ counts,
                           float* __restrict__ out) {
    __shared__ float partial[16];
    int t = threadIdx.x;  // 1024 threads
    float p = (float)counts[t] * (1.f / (float)N_ROWS);
    float v = (p > 0.f) ? p * logf(p) : 0.f;
    #pragma unroll
    for (int m = 32; m; m >>= 1) v += __shfl_xor(v, m, 64);
    if ((t & 63) == 0) partial[t >> 6] = v;
    __syncthreads();
    if (t < 16) {
        float s = partial[t];
        #pragma unroll
        for (int m = 8; m; m >>= 1) s += __shfl_xor(s, m, 16);
        if (t == 0) out[0] = expf(-s);
    }
}

extern "C" void kernel_launch(void* const* d_in, const int* in_sizes, int n_in,
                              void* d_out, int out_size, void* d_ws, size_t ws_size,
                              hipStream_t stream) {
    const float* z      = (const float*)d_in[0];
    const float* cb     = (const float*)d_in[1];
    const float* dither = (const float*)d_in[2];
    const float* n1     = (const float*)d_in[3];
    const float* n2     = (const float*)d_in[4];

    char* ws = (char*)d_ws;
    float*    dith    = (float*)(ws + DITH_OFF);
    float*    d2      = (float*)(ws + D2_OFF);
    unsigned* counts  = (unsigned*)(ws + CNT_OFF);
    int*      idx_arr = (int*)(ws + IDX_OFF);

    float* out  = (float*)d_out;
    float* zq   = out;
    float* idxf = out + (size_t)N_ROWS * DIM;
    float* ppl  = idxf + N_ROWS;

    prep_kernel<<<4, 256, 0, stream>>>(cb, dither, dith, d2, counts);
    argmin_kernel<<<N_ROWS / 256, 256, 0, stream>>>(z, dith, d2, idx_arr);
    finalize_kernel<<<N_ROWS / 4, 256, 0, stream>>>(z, cb, dither, n1, n2,
                                                    idx_arr, zq, idxf, counts);
    ppl_kernel<<<1, 1024, 0, stream>>>(counts, ppl);
}

// Round 3
// 470.915 us; speedup vs baseline: 1.6272x; 1.6272x over previous
//
#include <hip/hip_runtime.h>
#include <math.h>

#define N_ROWS 131072
#define DIM 64
#define KM1 1023
#define BK 64

// ---- ws layout (bytes) ----
#define DITH_OFF 0          // float[1023*64] = 261888, +1 row slack -> 262144
#define D2_OFF   262144     // float[1023]
#define CNT_OFF  266240     // u32[1024]
#define PACK_OFF 270336     // u64[131072] = 1 MB
// total ~1.29 MB

// Opacity guard: stops ffp-contract=fast from fusing mul into a following
// add (which would change rounding vs numpy's separate ops).
#define OPQ(x) asm volatile("" : "+v"(x))

typedef __attribute__((address_space(3))) float lds_float;

// Kernel A: dithered codebook (exact numpy op order), per-k dsum,
// zero counts, init packed argmin cells to UINT64_MAX.
__global__ void prep_kernel(const float* __restrict__ cb,
                            const float* __restrict__ dither,
                            float* __restrict__ dith,
                            float* __restrict__ d2,
                            unsigned* __restrict__ counts,
                            unsigned long long* __restrict__ packed) {
    int t = blockIdx.x * 256 + threadIdx.x;   // grid 512*256 = 131072
    packed[t] = ~0ull;
    if (t < 1024) counts[t] = 0u;
    if (t >= KM1) return;
    float tt = dither[t];
    float b[64];
    #pragma unroll 8
    for (int i = 0; i < 64; ++i) {
        float lo = cb[t * 64 + i];
        float hi = cb[t * 64 + 64 + i];
        float hl = __fsub_rn(hi, lo);
        float p  = __fmul_rn(tt, hl);
        OPQ(p);
        float dv = __fadd_rn(lo, p);
        OPQ(dv);
        dith[t * 64 + i] = dv;
        float bb = __fmul_rn(dv, dv);
        OPQ(bb);
        b[i] = bb;
    }
    // numpy pairwise_sum n=64: 8 accumulators stride-8, paired combine.
    float r[8];
    #pragma unroll
    for (int j = 0; j < 8; ++j) r[j] = b[j];
    #pragma unroll
    for (int i = 8; i < 64; i += 8) {
        #pragma unroll
        for (int j = 0; j < 8; ++j) r[j] = __fadd_rn(r[j], b[i + j]);
    }
    d2[t] = __fadd_rn(__fadd_rn(__fadd_rn(r[0], r[1]), __fadd_rn(r[2], r[3])),
                      __fadd_rn(__fadd_rn(r[4], r[5]), __fadd_rn(r[6], r[7])));
}

// Kernel B: per-row argmin, bit-exact numpy-replica scoring.
// Grid = 1024 blocks: blocks [0,512) do k=[0,512), blocks [512,1024) do
// k=[512,1023). dith streamed through double-buffered LDS (broadcast reads).
// Partial results merged via packed (float_bits<<32 | idx) atomicMin:
// D > 0 always, so uint order == float order; low bits give first-index
// tie-break (half A indices < half B indices).
__global__ void __launch_bounds__(256, 4)
argmin_kernel(const float* __restrict__ z_g,
              const float* __restrict__ dith,
              const float* __restrict__ d2g,
              unsigned long long* __restrict__ packed) {
    __shared__ float buf[2][BK * DIM];
    const int tid  = threadIdx.x;
    const int half = blockIdx.x >> 9;
    const int blk  = blockIdx.x & 511;
    const int row  = blk * 256 + tid;
    const int k0   = half * 512;
    const int nk   = half ? 511 : 512;
    const int NT   = 8;

    // z row -> 64 VGPRs (static indexing only).
    float z[DIM];
    const float4* zr = (const float4*)(z_g + (size_t)row * DIM);
    #pragma unroll 16
    for (int j = 0; j < 16; ++j) {
        float4 v = zr[j];
        z[4 * j + 0] = v.x; z[4 * j + 1] = v.y;
        z[4 * j + 2] = v.z; z[4 * j + 3] = v.w;
    }
    // zsum: numpy 8-accumulator pairwise over fl(z_i^2).
    float r[8];
    #pragma unroll 8
    for (int j = 0; j < 8; ++j) {
        float bb = __fmul_rn(z[j], z[j]); OPQ(bb); r[j] = bb;
    }
    #pragma unroll 7
    for (int i = 8; i < 64; i += 8) {
        #pragma unroll 8
        for (int j = 0; j < 8; ++j) {
            float bb = __fmul_rn(z[i + j], z[i + j]); OPQ(bb);
            r[j] = __fadd_rn(r[j], bb);
        }
    }
    float zsum = __fadd_rn(
        __fadd_rn(__fadd_rn(r[0], r[1]), __fadd_rn(r[2], r[3])),
        __fadd_rn(__fadd_rn(r[4], r[5]), __fadd_rn(r[6], r[7])));
    #pragma unroll 64
    for (int i = 0; i < 64; ++i) z[i] = __fadd_rn(z[i], z[i]);  // 2z exact

    // Prologue: stage tile 0.
    {
        const float4* src = (const float4*)(dith + (size_t)k0 * DIM);
        float4* dst = (float4*)buf[0];
        #pragma unroll 4
        for (int it = 0; it < 4; ++it) dst[it * 256 + tid] = src[it * 256 + tid];
    }
    __syncthreads();

    float best = INFINITY;
    int bidx = 0;
    int cur = 0;
    for (int t = 0; t < NT; ++t) {
        // Issue next tile's global loads early (latency hides under compute).
        float4 st0, st1, st2, st3;
        const bool more = (t + 1 < NT);
        if (more) {
            const float4* src =
                (const float4*)(dith + (size_t)(k0 + (t + 1) * BK) * DIM);
            st0 = src[0 * 256 + tid];
            st1 = src[1 * 256 + tid];
            st2 = src[2 * 256 + tid];
            st3 = src[3 * 256 + tid];
        }
        int tk = nk - t * BK; if (tk > BK) tk = BK;
        const float* B = buf[cur];
        int kk = 0;
        for (; kk + 4 <= tk; kk += 4) {
            const int gk = k0 + t * BK + kk;
            float e0 = d2g[gk], e1 = d2g[gk + 1], e2 = d2g[gk + 2], e3 = d2g[gk + 3];
            const float4* p0 = (const float4*)(B + (kk + 0) * DIM);
            const float4* p1 = (const float4*)(B + (kk + 1) * DIM);
            const float4* p2 = (const float4*)(B + (kk + 2) * DIM);
            const float4* p3 = (const float4*)(B + (kk + 3) * DIM);
            float a0 = 0.f, a1 = 0.f, a2 = 0.f, a3 = 0.f;
            #pragma unroll 16
            for (int i4 = 0; i4 < 16; ++i4) {
                float4 q0 = p0[i4], q1 = p1[i4], q2 = p2[i4], q3 = p3[i4];
                float z0 = z[4 * i4], z1 = z[4 * i4 + 1];
                float z2 = z[4 * i4 + 2], z3 = z[4 * i4 + 3];
                a0 = fmaf(z0, q0.x, a0); a1 = fmaf(z0, q1.x, a1);
                a2 = fmaf(z0, q2.x, a2); a3 = fmaf(z0, q3.x, a3);
                a0 = fmaf(z1, q0.y, a0); a1 = fmaf(z1, q1.y, a1);
                a2 = fmaf(z1, q2.y, a2); a3 = fmaf(z1, q3.y, a3);
                a0 = fmaf(z2, q0.z, a0); a1 = fmaf(z2, q1.z, a1);
                a2 = fmaf(z2, q2.z, a2); a3 = fmaf(z2, q3.z, a3);
                a0 = fmaf(z3, q0.w, a0); a1 = fmaf(z3, q1.w, a1);
                a2 = fmaf(z3, q2.w, a2); a3 = fmaf(z3, q3.w, a3);
            }
            float D0 = __fsub_rn(__fadd_rn(zsum, e0), a0);
            float D1 = __fsub_rn(__fadd_rn(zsum, e1), a1);
            float D2 = __fsub_rn(__fadd_rn(zsum, e2), a2);
            float D3 = __fsub_rn(__fadd_rn(zsum, e3), a3);
            if (D0 < best) { best = D0; bidx = gk; }
            if (D1 < best) { best = D1; bidx = gk + 1; }
            if (D2 < best) { best = D2; bidx = gk + 2; }
            if (D3 < best) { best = D3; bidx = gk + 3; }
        }
        for (; kk < tk; ++kk) {           // tail: only half B last tile (3 k)
            const int gk = k0 + t * BK + kk;
            float e0 = d2g[gk];
            const float4* p0 = (const float4*)(B + kk * DIM);
            float a0 = 0.f;
            #pragma unroll 16
            for (int i4 = 0; i4 < 16; ++i4) {
                float4 q0 = p0[i4];
                a0 = fmaf(z[4 * i4 + 0], q0.x, a0);
                a0 = fmaf(z[4 * i4 + 1], q0.y, a0);
                a0 = fmaf(z[4 * i4 + 2], q0.z, a0);
                a0 = fmaf(z[4 * i4 + 3], q0.w, a0);
            }
            float D0 = __fsub_rn(__fadd_rn(zsum, e0), a0);
            if (D0 < best) { best = D0; bidx = gk; }
        }
        if (more) {
            float4* dst = (float4*)buf[cur ^ 1];
            dst[0 * 256 + tid] = st0;
            dst[1 * 256 + tid] = st1;
            dst[2 * 256 + tid] = st2;
            dst[3 * 256 + tid] = st3;
        }
        __syncthreads();   // writes to buf[cur^1] visible; buf[cur] free
        cur ^= 1;
    }
    unsigned long long pk =
        ((unsigned long long)__float_as_uint(best) << 32) | (unsigned)bidx;
    atomicMin(packed + row, pk);
}

// Kernel C: per-row finalize. One wave per row (lane = dim).
__global__ void __launch_bounds__(256)
finalize_kernel(const float* __restrict__ z_g,
                const float* __restrict__ cb,
                const float* __restrict__ dither,
                const float* __restrict__ n1_g,
                const float* __restrict__ n2_g,
                const unsigned long long* __restrict__ packed,
                float* __restrict__ zq_out,
                float* __restrict__ idxf_out,
                unsigned* __restrict__ counts) {
    int wid = (blockIdx.x * 256 + threadIdx.x) >> 6;   // row
    int lane = threadIdx.x & 63;
    int idx = (int)(packed[wid] & 0xffffffffu);
    size_t base = (size_t)wid * DIM + lane;
    float z  = z_g[base];
    float n1 = n1_g[base];
    float n2 = n2_g[base];
    float c1 = cb[idx * DIM + lane];
    float c2 = cb[(idx + 1) * DIM + lane];
    float lam = dither[idx];
    float d1 = c1 - z, d2v = c2 - z;
    float r1 = n1 + d1, r2 = n2 + d2v;
    float s_r1 = r1 * r1, s_r2 = r2 * r2, s_d1 = d1 * d1, s_d2 = d2v * d2v;
    #pragma unroll
    for (int m = 32; m; m >>= 1) {
        s_r1 += __shfl_xor(s_r1, m, 64);
        s_r2 += __shfl_xor(s_r2, m, 64);
        s_d1 += __shfl_xor(s_d1, m, 64);
        s_d2 += __shfl_xor(s_d2, m, 64);
    }
    float em1 = sqrtf(s_d1), em2 = sqrtf(s_d2);
    float nr1 = fmaxf(sqrtf(s_r1), 1e-12f);
    float nr2 = fmaxf(sqrtf(s_r2), 1e-12f);
    float zq = z + em1 * (1.f - lam) * (r1 / nr1) + em2 * lam * (r2 / nr2);
    zq_out[base] = zq;
    if (lane == 0) {
        idxf_out[wid] = (float)idx;
        atomicAdd(&counts[idx], 1u);
    }
}

// Kernel D: perplexity from counts.
__global__ void ppl_kernel(const unsigned* __restrict__ counts,
                           float* __restrict__ out) {
    __shared__ float partial[16];
    int t = threadIdx.x;  // 1024 threads
    float p = (float)counts[t] * (1.f / (float)N_ROWS);
    float v = (p > 0.f) ? p * logf(p) : 0.f;
    #pragma unroll
    for (int m = 32; m; m >>= 1) v += __shfl_xor(v, m, 64);
    if ((t & 63) == 0) partial[t >> 6] = v;
    __syncthreads();
    if (t < 16) {
        float s = partial[t];
        #pragma unroll
        for (int m = 8; m; m >>= 1) s += __shfl_xor(s, m, 16);
        if (t == 0) out[0] = expf(-s);
    }
}

extern "C" void kernel_launch(void* const* d_in, const int* in_sizes, int n_in,
                              void* d_out, int out_size, void* d_ws, size_t ws_size,
                              hipStream_t stream) {
    const float* z      = (const float*)d_in[0];
    const float* cb     = (const float*)d_in[1];
    const float* dither = (const float*)d_in[2];
    const float* n1     = (const float*)d_in[3];
    const float* n2     = (const float*)d_in[4];

    char* ws = (char*)d_ws;
    float*              dith   = (float*)(ws + DITH_OFF);
    float*              d2     = (float*)(ws + D2_OFF);
    unsigned*           counts = (unsigned*)(ws + CNT_OFF);
    unsigned long long* packed = (unsigned long long*)(ws + PACK_OFF);

    float* out  = (float*)d_out;
    float* zq   = out;
    float* idxf = out + (size_t)N_ROWS * DIM;
    float* ppl  = idxf + N_ROWS;

    prep_kernel<<<512, 256, 0, stream>>>(cb, dither, dith, d2, counts, packed);
    argmin_kernel<<<1024, 256, 0, stream>>>(z, dith, d2, packed);
    finalize_kernel<<<N_ROWS / 4, 256, 0, stream>>>(z, cb, dither, n1, n2,
                                                    packed, zq, idxf, counts);
    ppl_kernel<<<1, 1024, 0, stream>>>(counts, ppl);
}